// Round 2
// baseline (762.070 us; speedup 1.0000x reference)
//
#include <hip/hip_runtime.h>
#include <math.h>

#define FIN 128

// ---------------------------------------------------------------------------
// helpers
// ---------------------------------------------------------------------------
__device__ __forceinline__ long long edge_at(const void* p, int i, unsigned mode) {
  // mode==1: int64 buffer, mode==0: int32 buffer
  return mode ? ((const long long*)p)[i] : (long long)((const int*)p)[i];
}

__device__ __forceinline__ void atomic_fadd(float* p, float v) {
  __hip_atomic_fetch_add(p, v, __ATOMIC_RELAXED, __HIP_MEMORY_SCOPE_AGENT);
}

// ---------------------------------------------------------------------------
// dtype detection: int64 edge_index has all-zero high words (values < 100000)
// ---------------------------------------------------------------------------
__global__ void k_detect(const unsigned* ei, unsigned* mode) {
  if (threadIdx.x == 0 && blockIdx.x == 0) {
    unsigned orv = 0;
    for (int i = 1; i < 1024; i += 2) orv |= ei[i];
    *mode = (orv == 0) ? 1u : 0u;
  }
}

// deg init = 1.0 (self-loop weight), zero the scalar accumulator
__global__ void k_init(float* deg, int n, float* acc) {
  int i = blockIdx.x * blockDim.x + threadIdx.x;
  if (i < n) deg[i] = 1.0f;
  if (i == 0 && blockIdx.x == 0) *acc = 0.0f;
}

// ---------------------------------------------------------------------------
// h = x @ conv_w   (wave per node: lane l handles elems l and l+64)
// ---------------------------------------------------------------------------
__global__ void k_h(const float* __restrict__ x, const float* __restrict__ cw,
                    float* __restrict__ h, int n) {
  int wid = (blockIdx.x * blockDim.x + threadIdx.x) >> 6;
  int lane = threadIdx.x & 63;
  if (wid >= n) return;
  float x0 = x[wid * FIN + lane];
  float x1 = x[wid * FIN + lane + 64];
  float s0 = x0 * cw[lane * 2]       + x1 * cw[(lane + 64) * 2];
  float s1 = x0 * cw[lane * 2 + 1]   + x1 * cw[(lane + 64) * 2 + 1];
  for (int off = 32; off > 0; off >>= 1) {
    s0 += __shfl_down(s0, off);
    s1 += __shfl_down(s1, off);
  }
  if (lane == 0) { h[wid * 2] = s0; h[wid * 2 + 1] = s1; }
}

// ---------------------------------------------------------------------------
// deg[col[e]] += attr[e]
// ---------------------------------------------------------------------------
__global__ void k_deg(const void* ei, const float* __restrict__ attr, float* deg,
                      int E, const unsigned* __restrict__ mode) {
  unsigned m = *mode;
  int stride = gridDim.x * blockDim.x;
  for (int e = blockIdx.x * blockDim.x + threadIdx.x; e < E; e += stride) {
    int c = (int)edge_at(ei, E + e, m);
    atomic_fadd(&deg[c], attr[e]);
  }
}

// dinv = rsqrt(deg); out = self-loop term + conv_b (full overwrite)
__global__ void k_dinv(float* dinv, const float* __restrict__ h,
                       const float* __restrict__ cb, float* __restrict__ out, int n) {
  int i = blockIdx.x * blockDim.x + threadIdx.x;
  if (i >= n) return;
  float d = dinv[i];
  float di = d > 0.f ? rsqrtf(d) : 0.f;
  dinv[i] = di;
  float w = di * di;
  out[2 * i]     = h[2 * i]     * w + cb[0];
  out[2 * i + 1] = h[2 * i + 1] * w + cb[1];
}

// out[col] += dinv[row]*attr*dinv[col] * h[row]
__global__ void k_msg(const void* ei, const float* __restrict__ attr,
                      const float* __restrict__ dinv, const float* __restrict__ h,
                      float* out, int E, const unsigned* __restrict__ mode) {
  unsigned m = *mode;
  int stride = gridDim.x * blockDim.x;
  for (int e = blockIdx.x * blockDim.x + threadIdx.x; e < E; e += stride) {
    int r = (int)edge_at(ei, e, m);
    int c = (int)edge_at(ei, E + e, m);
    float nrm = dinv[r] * attr[e] * dinv[c];
    atomic_fadd(&out[2 * c],     nrm * h[2 * r]);
    atomic_fadd(&out[2 * c + 1], nrm * h[2 * r + 1]);
  }
}

// ---------------------------------------------------------------------------
// relu (in place), score = tanh((out.pw)/|pw|), build descending sort keys
// ---------------------------------------------------------------------------
__global__ void k_score(float* out, const float* __restrict__ pw, float* score,
                        unsigned* keys, unsigned* pay, int n) {
  int i = blockIdx.x * blockDim.x + threadIdx.x;
  if (i >= n) return;
  float o0 = fmaxf(out[2 * i], 0.f), o1 = fmaxf(out[2 * i + 1], 0.f);
  out[2 * i] = o0; out[2 * i + 1] = o1;
  float pw0 = pw[0], pw1 = pw[1];
  float nrm = sqrtf(pw0 * pw0 + pw1 * pw1);
  float s = tanhf((o0 * pw0 + o1 * pw1) / nrm);
  score[i] = s;
  unsigned u = __float_as_uint(s);
  unsigned asc = u ^ ((u >> 31) ? 0xFFFFFFFFu : 0x80000000u);
  keys[i] = ~asc;          // descending-order key, sort ascending
  pay[i] = (unsigned)i;
}

// ---------------------------------------------------------------------------
// stable LSD radix sort, 4 x 8-bit passes, chunk=1024/block
// ---------------------------------------------------------------------------
__global__ void k_radix_hist(const unsigned* __restrict__ keys, int n, int shift,
                             unsigned* table) {
  __shared__ unsigned hist[256];
  int t = threadIdx.x;
  hist[t] = 0;
  __syncthreads();
  int base = blockIdx.x * 1024;
  for (int j = 0; j < 4; ++j) {
    int g = base + j * 256 + t;
    if (g < n) {
      unsigned d = (keys[g] >> shift) & 255u;
      atomicAdd(&hist[d], 1u);
    }
  }
  __syncthreads();
  table[t * gridDim.x + blockIdx.x] = hist[t];   // digit-major layout
}

__global__ void k_radix_scan(unsigned* table, int B) {
  __shared__ unsigned partials[256];
  int t = threadIdx.x;
  int s = t * B;
  unsigned sum = 0;
  for (int i = 0; i < B; ++i) sum += table[s + i];
  partials[t] = sum;
  __syncthreads();
  unsigned pre = 0;
  for (int i = 0; i < t; ++i) pre += partials[i];
  unsigned run = pre;
  for (int i = 0; i < B; ++i) { unsigned v = table[s + i]; table[s + i] = run; run += v; }
}

__global__ void k_radix_scatter(const unsigned* __restrict__ keysIn,
                                const unsigned* __restrict__ payIn, int n, int shift,
                                const unsigned* __restrict__ table,
                                unsigned* keysOut, unsigned* payOut) {
  __shared__ unsigned runCnt[256];
  __shared__ unsigned waveCnt[4 * 256];
  int t = threadIdx.x;
  int lane = t & 63, w = t >> 6;
  int B = gridDim.x;
  runCnt[t] = 0;
  int base = blockIdx.x * 1024;
  for (int j = 0; j < 4; ++j) {
    for (int q = t; q < 1024; q += 256) waveCnt[q] = 0;
    __syncthreads();
    int g = base + j * 256 + t;
    bool active = g < n;
    unsigned key = 0, pay = 0, d = 0;
    if (active) { key = keysIn[g]; pay = payIn[g]; d = (key >> shift) & 255u; }
    unsigned long long am = __ballot(active);
    unsigned long long mm = ~0ull;
#pragma unroll
    for (int b = 0; b < 8; ++b) {
      unsigned long long bb = __ballot((d >> b) & 1u);
      mm &= ((d >> b) & 1u) ? bb : ~bb;
    }
    mm &= am;
    int rankw = __popcll(mm & ((1ull << lane) - 1ull));
    if (active && rankw == 0) waveCnt[w * 256 + d] = (unsigned)__popcll(mm);
    __syncthreads();
    if (active) {
      unsigned off = runCnt[d] + (unsigned)rankw;
      for (int ww = 0; ww < w; ++ww) off += waveCnt[ww * 256 + d];
      unsigned gpos = table[d * B + blockIdx.x] + off;
      keysOut[gpos] = key;
      payOut[gpos] = pay;
    }
    __syncthreads();
    runCnt[t] += waveCnt[t] + waveCnt[256 + t] + waveCnt[512 + t] + waveCnt[768 + t];
    __syncthreads();
  }
}

// ---------------------------------------------------------------------------
// y-pre = sum_j score[perm[j]] * (out[perm[j]] . fc_w[2j:2j+2])
// ---------------------------------------------------------------------------
__global__ void k_final(const unsigned* __restrict__ perm, const float* __restrict__ out,
                        const float* __restrict__ score, const float* __restrict__ fcw,
                        float* acc, int n) {
  int stride = gridDim.x * blockDim.x;
  float s = 0.f;
  for (int j = blockIdx.x * blockDim.x + threadIdx.x; j < n; j += stride) {
    unsigned p = perm[j];
    float sc = score[p];
    s += sc * (out[2 * p] * fcw[2 * j] + out[2 * p + 1] * fcw[2 * j + 1]);
  }
  for (int off = 32; off > 0; off >>= 1) s += __shfl_down(s, off);
  if ((threadIdx.x & 63) == 0) atomic_fadd(acc, s);
}

__global__ void k_sigmoid(const float* acc, const float* __restrict__ fcb, float* y) {
  if (threadIdx.x == 0 && blockIdx.x == 0) {
    float z = *acc + fcb[0];
    y[0] = 1.f / (1.f + expf(-z));
  }
}

// ---------------------------------------------------------------------------
extern "C" void kernel_launch(void* const* d_in, const int* in_sizes, int n_in,
                              void* d_out, int out_size, void* d_ws, size_t ws_size,
                              hipStream_t stream) {
  const float* x     = (const float*)d_in[0];
  const void*  ei    = d_in[1];
  const float* attr  = (const float*)d_in[2];
  const float* convw = (const float*)d_in[3];
  const float* convb = (const float*)d_in[4];
  const float* poolw = (const float*)d_in[5];
  const float* fcw   = (const float*)d_in[6];
  const float* fcb   = (const float*)d_in[7];
  float* y = (float*)d_out;

  int N = in_sizes[0] / FIN;      // 100000
  int E = in_sizes[2];            // 3200000
  int B = (N + 1023) / 1024;      // radix chunks (98)

  // workspace carve (all 4-byte elements)
  float* ws = (float*)d_ws;
  size_t off = 0;
  float* h      = ws + off; off += (size_t)2 * N;
  float* dinv   = ws + off; off += (size_t)N;       // holds deg, then dinv
  float* outN   = ws + off; off += (size_t)2 * N;
  float* score  = ws + off; off += (size_t)N;
  unsigned* keysA = (unsigned*)(ws + off); off += (size_t)N;
  unsigned* payA  = (unsigned*)(ws + off); off += (size_t)N;
  unsigned* keysB = (unsigned*)(ws + off); off += (size_t)N;
  unsigned* payB  = (unsigned*)(ws + off); off += (size_t)N;
  unsigned* table = (unsigned*)(ws + off); off += (size_t)256 * B;
  float* acc      = ws + off; off += 1;
  unsigned* mode  = (unsigned*)(ws + off); off += 1;

  int nb = (N + 255) / 256;

  k_detect<<<1, 64, 0, stream>>>((const unsigned*)ei, mode);
  k_init<<<nb, 256, 0, stream>>>(dinv, N, acc);
  k_h<<<(N + 3) / 4, 256, 0, stream>>>(x, convw, h, N);
  k_deg<<<2048, 256, 0, stream>>>(ei, attr, dinv, E, mode);
  k_dinv<<<nb, 256, 0, stream>>>(dinv, h, convb, outN, N);
  k_msg<<<2048, 256, 0, stream>>>(ei, attr, dinv, h, outN, E, mode);
  k_score<<<nb, 256, 0, stream>>>(outN, poolw, score, keysA, payA, N);

  // 4 stable radix passes: A->B->A->B->A
  unsigned* ki = keysA; unsigned* pi = payA;
  unsigned* ko = keysB; unsigned* po = payB;
  for (int p = 0; p < 4; ++p) {
    int shift = 8 * p;
    k_radix_hist<<<B, 256, 0, stream>>>(ki, N, shift, table);
    k_radix_scan<<<1, 256, 0, stream>>>(table, B);
    k_radix_scatter<<<B, 256, 0, stream>>>(ki, pi, N, shift, table, ko, po);
    unsigned* tk = ki; ki = ko; ko = tk;
    unsigned* tp = pi; pi = po; po = tp;
  }
  // result (perm) now in payA == pi

  k_final<<<98, 256, 0, stream>>>(pi, outN, score, fcw, acc, N);
  k_sigmoid<<<1, 64, 0, stream>>>(acc, fcb, y);
}

// Round 3
// 392.299 us; speedup vs baseline: 1.9426x; 1.9426x over previous
//
#include <hip/hip_runtime.h>
#include <math.h>

#define FIN 128
#define MAXBUK 3328   // LDS counter capacity (need 3125)
#define HB 256        // hist/scatter blocks
#define HT 1024       // hist/scatter threads per block

// ---------------------------------------------------------------------------
// helpers
// ---------------------------------------------------------------------------
__device__ __forceinline__ long long edge_at(const void* p, long long i, unsigned mode) {
  // mode==1: int64 buffer, mode==0: int32 buffer
  return mode ? ((const long long*)p)[i] : (long long)((const int*)p)[i];
}

__device__ __forceinline__ void atomic_fadd(float* p, float v) {
  __hip_atomic_fetch_add(p, v, __ATOMIC_RELAXED, __HIP_MEMORY_SCOPE_AGENT);
}

// ---------------------------------------------------------------------------
// dtype detection: int64 edge_index has all-zero high words (values < 100000)
// also zeroes the final-dot accumulator
// ---------------------------------------------------------------------------
__global__ void k_detect(const unsigned* ei, unsigned* mode, float* acc) {
  if (threadIdx.x == 0 && blockIdx.x == 0) {
    unsigned orv = 0;
    for (int i = 1; i < 1024; i += 2) orv |= ei[i];
    *mode = (orv == 0) ? 1u : 0u;
    *acc = 0.0f;
  }
}

// ---------------------------------------------------------------------------
// h = x @ conv_w   (wave per node: lane l handles elems l and l+64)
// ---------------------------------------------------------------------------
__global__ void k_h(const float* __restrict__ x, const float* __restrict__ cw,
                    float* __restrict__ h, int n) {
  int wid = (blockIdx.x * blockDim.x + threadIdx.x) >> 6;
  int lane = threadIdx.x & 63;
  if (wid >= n) return;
  float x0 = x[wid * FIN + lane];
  float x1 = x[wid * FIN + lane + 64];
  float s0 = x0 * cw[lane * 2]       + x1 * cw[(lane + 64) * 2];
  float s1 = x0 * cw[lane * 2 + 1]   + x1 * cw[(lane + 64) * 2 + 1];
  for (int off = 32; off > 0; off >>= 1) {
    s0 += __shfl_down(s0, off);
    s1 += __shfl_down(s1, off);
  }
  if (lane == 0) { h[wid * 2] = s0; h[wid * 2 + 1] = s1; }
}

// ---------------------------------------------------------------------------
// edge bucketing: bucket = col >> 5  (32 destination nodes per bucket)
// ---------------------------------------------------------------------------
__global__ void k_hist(const void* ei, long long E, int nbuk,
                       unsigned* table, const unsigned* __restrict__ mode) {
  __shared__ unsigned hist[MAXBUK];
  unsigned m = *mode;
  int t = threadIdx.x;
  for (int i = t; i < nbuk; i += HT) hist[i] = 0;
  __syncthreads();
  long long perB = (E + HB - 1) / HB;
  long long base = (long long)blockIdx.x * perB;
  long long lim = base + perB; if (lim > E) lim = E;
  for (long long e = base + t; e < lim; e += HT) {
    int c = (int)edge_at(ei, E + e, m);
    atomicAdd(&hist[c >> 5], 1u);
  }
  __syncthreads();
  for (int i = t; i < nbuk; i += HT) table[(size_t)i * HB + blockIdx.x] = hist[i];
}

__global__ void k_bsum(const unsigned* __restrict__ table, unsigned* btot) {
  int b = blockIdx.x, t = threadIdx.x;
  unsigned v = table[(size_t)b * HB + t];
  for (int off = 32; off > 0; off >>= 1) v += __shfl_down(v, off);
  __shared__ unsigned wsum[4];
  if ((t & 63) == 0) wsum[t >> 6] = v;
  __syncthreads();
  if (t == 0) btot[b] = wsum[0] + wsum[1] + wsum[2] + wsum[3];
}

__global__ void k_bscan(const unsigned* __restrict__ btot, unsigned* boff,
                        int nbuk, int chunk, unsigned total) {
  __shared__ unsigned part[256];
  int t = threadIdx.x;
  int c0 = t * chunk, c1 = c0 + chunk; if (c1 > nbuk) c1 = nbuk;
  unsigned s = 0;
  for (int i = c0; i < c1; ++i) s += btot[i];
  part[t] = s;
  __syncthreads();
  unsigned pre = 0;
  for (int i = 0; i < t; ++i) pre += part[i];
  unsigned run = pre;
  for (int i = c0; i < c1; ++i) { boff[i] = run; run += btot[i]; }
  if (t == 255) boff[nbuk] = total;
}

__global__ void k_bapply(unsigned* table, const unsigned* __restrict__ boff) {
  __shared__ unsigned s[256];
  int b = blockIdx.x, t = threadIdx.x;
  unsigned v = table[(size_t)b * HB + t];
  s[t] = v;
  __syncthreads();
  for (int off = 1; off < 256; off <<= 1) {
    unsigned tmp = (t >= off) ? s[t - off] : 0u;
    __syncthreads();
    s[t] += tmp;
    __syncthreads();
  }
  table[(size_t)b * HB + t] = s[t] - v + boff[b];
}

__global__ void k_scatter(const void* ei, const float* __restrict__ attr,
                          long long E, int nbuk, const unsigned* __restrict__ table,
                          uint2* __restrict__ packed, const unsigned* __restrict__ mode) {
  __shared__ unsigned cur[MAXBUK];
  unsigned m = *mode;
  int t = threadIdx.x;
  for (int i = t; i < nbuk; i += HT) cur[i] = table[(size_t)i * HB + blockIdx.x];
  __syncthreads();
  long long perB = (E + HB - 1) / HB;
  long long base = (long long)blockIdx.x * perB;
  long long lim = base + perB; if (lim > E) lim = E;
  for (long long e = base + t; e < lim; e += HT) {
    int r = (int)edge_at(ei, e, m);
    int c = (int)edge_at(ei, E + e, m);
    float a = attr[e];
    unsigned pos = atomicAdd(&cur[c >> 5], 1u);
    packed[pos] = make_uint2(((unsigned)r << 5) | ((unsigned)c & 31u), __float_as_uint(a));
  }
}

// ---------------------------------------------------------------------------
// per-bucket degree: deg[c] = 1 (self loop) + sum attr of incoming edges
// ---------------------------------------------------------------------------
__global__ void k_bdeg(const uint2* __restrict__ packed, const unsigned* __restrict__ boff,
                       float* __restrict__ deg, int n) {
  __shared__ float sdeg[32];
  int b = blockIdx.x, t = threadIdx.x;
  if (t < 32) sdeg[t] = 1.0f;
  __syncthreads();
  unsigned s0 = boff[b], s1 = boff[b + 1];
  for (unsigned i = s0 + t; i < s1; i += 256) {
    uint2 p = packed[i];
    atomicAdd(&sdeg[p.x & 31u], __uint_as_float(p.y));
  }
  __syncthreads();
  if (t < 32) {
    int c = b * 32 + t;
    if (c < n) deg[c] = sdeg[t];
  }
}

// dinv = rsqrt(deg) (deg >= 1 always); g[r] = dinv[r] * h[r]
__global__ void k_dinv(const float* __restrict__ deg, const float* __restrict__ h,
                       float* __restrict__ dinv, float* __restrict__ g, int n) {
  int i = blockIdx.x * blockDim.x + threadIdx.x;
  if (i >= n) return;
  float di = rsqrtf(deg[i]);
  dinv[i] = di;
  g[2 * i]     = di * h[2 * i];
  g[2 * i + 1] = di * h[2 * i + 1];
}

// per-bucket messages: out[c] = dinv[c]*sum(attr*g[r]) + dinv[c]^2*h[c] + bias
__global__ void k_bmsg(const uint2* __restrict__ packed, const unsigned* __restrict__ boff,
                       const float* __restrict__ g, const float* __restrict__ dinv,
                       const float* __restrict__ h, const float* __restrict__ cb,
                       float* __restrict__ out, int n) {
  __shared__ float sacc[64];
  int b = blockIdx.x, t = threadIdx.x;
  if (t < 64) sacc[t] = 0.0f;
  __syncthreads();
  unsigned s0 = boff[b], s1 = boff[b + 1];
  const float2* g2 = (const float2*)g;
  for (unsigned i = s0 + t; i < s1; i += 256) {
    uint2 p = packed[i];
    unsigned r = p.x >> 5;
    unsigned cl = p.x & 31u;
    float a = __uint_as_float(p.y);
    float2 gr = g2[r];
    atomicAdd(&sacc[cl * 2],     a * gr.x);
    atomicAdd(&sacc[cl * 2 + 1], a * gr.y);
  }
  __syncthreads();
  if (t < 32) {
    int c = b * 32 + t;
    if (c < n) {
      float dc = dinv[c];
      out[2 * c]     = dc * sacc[2 * t]     + dc * dc * h[2 * c]     + cb[0];
      out[2 * c + 1] = dc * sacc[2 * t + 1] + dc * dc * h[2 * c + 1] + cb[1];
    }
  }
}

// ---------------------------------------------------------------------------
// relu (in place), score = tanh((out.pw)/|pw|), build descending sort keys
// ---------------------------------------------------------------------------
__global__ void k_score(float* out, const float* __restrict__ pw, float* score,
                        unsigned* keys, unsigned* pay, int n) {
  int i = blockIdx.x * blockDim.x + threadIdx.x;
  if (i >= n) return;
  float o0 = fmaxf(out[2 * i], 0.f), o1 = fmaxf(out[2 * i + 1], 0.f);
  out[2 * i] = o0; out[2 * i + 1] = o1;
  float pw0 = pw[0], pw1 = pw[1];
  float nrm = sqrtf(pw0 * pw0 + pw1 * pw1);
  float s = tanhf((o0 * pw0 + o1 * pw1) / nrm);
  score[i] = s;
  unsigned u = __float_as_uint(s);
  unsigned asc = u ^ ((u >> 31) ? 0xFFFFFFFFu : 0x80000000u);
  keys[i] = ~asc;          // descending-order key, sort ascending
  pay[i] = (unsigned)i;
}

// ---------------------------------------------------------------------------
// stable LSD radix sort, 4 x 8-bit passes, chunk=1024/block
// ---------------------------------------------------------------------------
__global__ void k_radix_hist(const unsigned* __restrict__ keys, int n, int shift,
                             unsigned* table) {
  __shared__ unsigned hist[256];
  int t = threadIdx.x;
  hist[t] = 0;
  __syncthreads();
  int base = blockIdx.x * 1024;
  for (int j = 0; j < 4; ++j) {
    int g = base + j * 256 + t;
    if (g < n) {
      unsigned d = (keys[g] >> shift) & 255u;
      atomicAdd(&hist[d], 1u);
    }
  }
  __syncthreads();
  table[t * gridDim.x + blockIdx.x] = hist[t];   // digit-major layout
}

__global__ void k_radix_scan(unsigned* table, int B) {
  __shared__ unsigned partials[256];
  int t = threadIdx.x;
  int s = t * B;
  unsigned sum = 0;
  for (int i = 0; i < B; ++i) sum += table[s + i];
  partials[t] = sum;
  __syncthreads();
  unsigned pre = 0;
  for (int i = 0; i < t; ++i) pre += partials[i];
  unsigned run = pre;
  for (int i = 0; i < B; ++i) { unsigned v = table[s + i]; table[s + i] = run; run += v; }
}

__global__ void k_radix_scatter(const unsigned* __restrict__ keysIn,
                                const unsigned* __restrict__ payIn, int n, int shift,
                                const unsigned* __restrict__ table,
                                unsigned* keysOut, unsigned* payOut) {
  __shared__ unsigned runCnt[256];
  __shared__ unsigned waveCnt[4 * 256];
  int t = threadIdx.x;
  int lane = t & 63, w = t >> 6;
  int B = gridDim.x;
  runCnt[t] = 0;
  int base = blockIdx.x * 1024;
  for (int j = 0; j < 4; ++j) {
    for (int q = t; q < 1024; q += 256) waveCnt[q] = 0;
    __syncthreads();
    int g = base + j * 256 + t;
    bool active = g < n;
    unsigned key = 0, pay = 0, d = 0;
    if (active) { key = keysIn[g]; pay = payIn[g]; d = (key >> shift) & 255u; }
    unsigned long long am = __ballot(active);
    unsigned long long mm = ~0ull;
#pragma unroll
    for (int b = 0; b < 8; ++b) {
      unsigned long long bb = __ballot((d >> b) & 1u);
      mm &= ((d >> b) & 1u) ? bb : ~bb;
    }
    mm &= am;
    int rankw = __popcll(mm & ((1ull << lane) - 1ull));
    if (active && rankw == 0) waveCnt[w * 256 + d] = (unsigned)__popcll(mm);
    __syncthreads();
    if (active) {
      unsigned off = runCnt[d] + (unsigned)rankw;
      for (int ww = 0; ww < w; ++ww) off += waveCnt[ww * 256 + d];
      unsigned gpos = table[d * B + blockIdx.x] + off;
      keysOut[gpos] = key;
      payOut[gpos] = pay;
    }
    __syncthreads();
    runCnt[t] += waveCnt[t] + waveCnt[256 + t] + waveCnt[512 + t] + waveCnt[768 + t];
    __syncthreads();
  }
}

// ---------------------------------------------------------------------------
// y-pre = sum_j score[perm[j]] * (out[perm[j]] . fc_w[2j:2j+2])
// ---------------------------------------------------------------------------
__global__ void k_final(const unsigned* __restrict__ perm, const float* __restrict__ out,
                        const float* __restrict__ score, const float* __restrict__ fcw,
                        float* acc, int n) {
  int stride = gridDim.x * blockDim.x;
  float s = 0.f;
  for (int j = blockIdx.x * blockDim.x + threadIdx.x; j < n; j += stride) {
    unsigned p = perm[j];
    float sc = score[p];
    s += sc * (out[2 * p] * fcw[2 * j] + out[2 * p + 1] * fcw[2 * j + 1]);
  }
  for (int off = 32; off > 0; off >>= 1) s += __shfl_down(s, off);
  if ((threadIdx.x & 63) == 0) atomic_fadd(acc, s);
}

__global__ void k_sigmoid(const float* acc, const float* __restrict__ fcb, float* y) {
  if (threadIdx.x == 0 && blockIdx.x == 0) {
    float z = *acc + fcb[0];
    y[0] = 1.f / (1.f + expf(-z));
  }
}

// ---------------------------------------------------------------------------
extern "C" void kernel_launch(void* const* d_in, const int* in_sizes, int n_in,
                              void* d_out, int out_size, void* d_ws, size_t ws_size,
                              hipStream_t stream) {
  const float* x     = (const float*)d_in[0];
  const void*  ei    = d_in[1];
  const float* attr  = (const float*)d_in[2];
  const float* convw = (const float*)d_in[3];
  const float* convb = (const float*)d_in[4];
  const float* poolw = (const float*)d_in[5];
  const float* fcw   = (const float*)d_in[6];
  const float* fcb   = (const float*)d_in[7];
  float* y = (float*)d_out;

  int N = in_sizes[0] / FIN;      // 100000
  long long E = in_sizes[2];      // 3200000
  int B = (N + 1023) / 1024;      // score radix chunks (98)
  int nbuk = (N + 31) / 32;       // 3125 edge buckets

  // workspace carve (4-byte units; keep 8B alignment for uint2/float2 arrays)
  float* ws = (float*)d_ws;
  size_t off = 0;
  uint2* packed  = (uint2*)(ws + off); off += (size_t)2 * E;   // 8B-aligned (off=0)
  float* h       = ws + off; off += (size_t)2 * N;
  float* deg     = ws + off; off += (size_t)N;
  float* dinv    = ws + off; off += (size_t)N;
  float* g       = ws + off; off += (size_t)2 * N;             // even offset -> 8B aligned
  float* outN    = ws + off; off += (size_t)2 * N;
  float* score   = ws + off; off += (size_t)N;
  unsigned* keysA = (unsigned*)(ws + off); off += (size_t)N;
  unsigned* payA  = (unsigned*)(ws + off); off += (size_t)N;
  unsigned* keysB = (unsigned*)(ws + off); off += (size_t)N;
  unsigned* payB  = (unsigned*)(ws + off); off += (size_t)N;
  unsigned* etab  = (unsigned*)(ws + off); off += (size_t)nbuk * HB;
  unsigned* btot  = (unsigned*)(ws + off); off += (size_t)nbuk;
  unsigned* boff  = (unsigned*)(ws + off); off += (size_t)nbuk + 2;
  unsigned* stab  = (unsigned*)(ws + off); off += (size_t)256 * B;
  float* acc      = ws + off; off += 1;
  unsigned* mode  = (unsigned*)(ws + off); off += 1;

  int nb = (N + 255) / 256;
  int chunk = (nbuk + 255) / 256;

  k_detect<<<1, 64, 0, stream>>>((const unsigned*)ei, mode, acc);
  k_h<<<(N + 3) / 4, 256, 0, stream>>>(x, convw, h, N);

  // ---- edge bucketing by destination ----
  k_hist<<<HB, HT, 0, stream>>>(ei, E, nbuk, etab, mode);
  k_bsum<<<nbuk, 256, 0, stream>>>(etab, btot);
  k_bscan<<<1, 256, 0, stream>>>(btot, boff, nbuk, chunk, (unsigned)E);
  k_bapply<<<nbuk, 256, 0, stream>>>(etab, boff);
  k_scatter<<<HB, HT, 0, stream>>>(ei, attr, E, nbuk, etab, packed, mode);

  // ---- GCN conv via bucketed, atomic-free accumulation ----
  k_bdeg<<<nbuk, 256, 0, stream>>>(packed, boff, deg, N);
  k_dinv<<<nb, 256, 0, stream>>>(deg, h, dinv, g, N);
  k_bmsg<<<nbuk, 256, 0, stream>>>(packed, boff, g, dinv, h, convb, outN, N);

  k_score<<<nb, 256, 0, stream>>>(outN, poolw, score, keysA, payA, N);

  // 4 stable radix passes: A->B->A->B->A
  unsigned* ki = keysA; unsigned* pi = payA;
  unsigned* ko = keysB; unsigned* po = payB;
  for (int p = 0; p < 4; ++p) {
    int shift = 8 * p;
    k_radix_hist<<<B, 256, 0, stream>>>(ki, N, shift, stab);
    k_radix_scan<<<1, 256, 0, stream>>>(stab, B);
    k_radix_scatter<<<B, 256, 0, stream>>>(ki, pi, N, shift, stab, ko, po);
    unsigned* tk = ki; ki = ko; ko = tk;
    unsigned* tp = pi; pi = po; po = tp;
  }
  // perm now in pi (== payA)

  k_final<<<98, 256, 0, stream>>>(pi, outN, score, fcw, acc, N);
  k_sigmoid<<<1, 64, 0, stream>>>(acc, fcb, y);
}

// Round 4
// 235.521 us; speedup vs baseline: 3.2357x; 1.6657x over previous
//
#include <hip/hip_runtime.h>
#include <math.h>

#define FIN 128
#define W 512          // nodes per coarse group
#define MAXG 256       // LDS counter capacity (need G=196)
#define HB 256         // edge hist/scatter blocks
#define HT 1024        // edge hist/scatter threads per block
#define BP 100         // radix table padded stride (>= B=98, mult of 4)

// ---------------------------------------------------------------------------
// helpers
// ---------------------------------------------------------------------------
__device__ __forceinline__ long long edge_at(const void* p, long long i, unsigned mode) {
  return mode ? ((const long long*)p)[i] : (long long)((const int*)p)[i];
}

__device__ __forceinline__ void atomic_fadd(float* p, float v) {
  __hip_atomic_fetch_add(p, v, __ATOMIC_RELAXED, __HIP_MEMORY_SCOPE_AGENT);
}

// ---------------------------------------------------------------------------
// dtype detection: int64 edge_index has all-zero high words (values < 100000)
// ---------------------------------------------------------------------------
__global__ void k_detect(const unsigned* ei, unsigned* mode, float* acc) {
  if (threadIdx.x == 0 && blockIdx.x == 0) {
    unsigned orv = 0;
    for (int i = 1; i < 1024; i += 2) orv |= ei[i];
    *mode = (orv == 0) ? 1u : 0u;
    *acc = 0.0f;
  }
}

// ---------------------------------------------------------------------------
// h = x @ conv_w   (32 threads per node, float4 loads)
// ---------------------------------------------------------------------------
__global__ void k_h(const float* __restrict__ x, const float* __restrict__ cw,
                    float* __restrict__ h, int n) {
  int gt = blockIdx.x * blockDim.x + threadIdx.x;
  int node = gt >> 5;
  int sub = gt & 31;
  if (node >= n) return;
  float4 xv = ((const float4*)x)[node * 32 + sub];
  float s0 = xv.x * cw[sub * 8 + 0] + xv.y * cw[sub * 8 + 2] +
             xv.z * cw[sub * 8 + 4] + xv.w * cw[sub * 8 + 6];
  float s1 = xv.x * cw[sub * 8 + 1] + xv.y * cw[sub * 8 + 3] +
             xv.z * cw[sub * 8 + 5] + xv.w * cw[sub * 8 + 7];
  for (int off = 16; off > 0; off >>= 1) {
    s0 += __shfl_down(s0, off, 32);
    s1 += __shfl_down(s1, off, 32);
  }
  if (sub == 0) { h[node * 2] = s0; h[node * 2 + 1] = s1; }
}

// ---------------------------------------------------------------------------
// edge bucketing: group = col >> 9  (512 destination nodes per group)
// ---------------------------------------------------------------------------
__global__ void k_hist(const void* ei, long long E, int G,
                       unsigned* table, const unsigned* __restrict__ mode) {
  __shared__ unsigned hist[MAXG];
  unsigned m = *mode;
  int t = threadIdx.x;
  if (t < MAXG) hist[t] = 0;
  __syncthreads();
  long long perB = (E + HB - 1) / HB;
  long long base = (long long)blockIdx.x * perB;
  long long lim = base + perB; if (lim > E) lim = E;
  for (long long e = base + t; e < lim; e += HT) {
    int c = (int)edge_at(ei, E + e, m);
    atomicAdd(&hist[c >> 9], 1u);
  }
  __syncthreads();
  if (t < G) table[(size_t)t * HB + blockIdx.x] = hist[t];
}

__global__ void k_bsum(const unsigned* __restrict__ table, unsigned* btot) {
  int b = blockIdx.x, t = threadIdx.x;
  unsigned v = table[(size_t)b * HB + t];
  for (int off = 32; off > 0; off >>= 1) v += __shfl_down(v, off);
  __shared__ unsigned wsum[4];
  if ((t & 63) == 0) wsum[t >> 6] = v;
  __syncthreads();
  if (t == 0) btot[b] = wsum[0] + wsum[1] + wsum[2] + wsum[3];
}

__global__ void k_bscan(const unsigned* __restrict__ btot, unsigned* boff,
                        int G, int chunk, unsigned total) {
  __shared__ unsigned part[256];
  int t = threadIdx.x;
  int c0 = t * chunk, c1 = c0 + chunk; if (c1 > G) c1 = G;
  unsigned s = 0;
  for (int i = c0; i < c1; ++i) s += btot[i];
  part[t] = s;
  __syncthreads();
  unsigned pre = 0;
  for (int i = 0; i < t; ++i) pre += part[i];
  unsigned run = pre;
  for (int i = c0; i < c1; ++i) { boff[i] = run; run += btot[i]; }
  if (t == 255) boff[G] = total;
}

__global__ void k_bapply(unsigned* table, const unsigned* __restrict__ boff) {
  __shared__ unsigned s[256];
  int b = blockIdx.x, t = threadIdx.x;
  unsigned v = table[(size_t)b * HB + t];
  s[t] = v;
  __syncthreads();
  for (int off = 1; off < 256; off <<= 1) {
    unsigned tmp = (t >= off) ? s[t - off] : 0u;
    __syncthreads();
    s[t] += tmp;
    __syncthreads();
  }
  table[(size_t)b * HB + t] = s[t] - v + boff[b];
}

// scatter edges into coarse-group order; per-(group,block) runs are contiguous
// (~512B) so L2 write-combines full lines within one XCD.
__global__ void k_scatter(const void* ei, const float* __restrict__ attr,
                          long long E, int G, const unsigned* __restrict__ table,
                          uint2* __restrict__ packed, const unsigned* __restrict__ mode) {
  __shared__ unsigned cur[MAXG];
  unsigned m = *mode;
  int t = threadIdx.x;
  if (t < G) cur[t] = table[(size_t)t * HB + blockIdx.x];
  __syncthreads();
  long long perB = (E + HB - 1) / HB;
  long long base = (long long)blockIdx.x * perB;
  long long lim = base + perB; if (lim > E) lim = E;
  for (long long e = base + t; e < lim; e += HT) {
    int r = (int)edge_at(ei, e, m);
    int c = (int)edge_at(ei, E + e, m);
    float a = attr[e];
    unsigned pos = atomicAdd(&cur[c >> 9], 1u);
    packed[pos] = make_uint2(((unsigned)r << 9) | ((unsigned)c & 511u), __float_as_uint(a));
  }
}

// ---------------------------------------------------------------------------
// per-group degree: deg[c] = 1 (self loop) + sum attr of incoming edges
// ---------------------------------------------------------------------------
__global__ void k_gdeg(const uint2* __restrict__ packed, const unsigned* __restrict__ boff,
                       float* __restrict__ deg, int n) {
  __shared__ float sdeg[W];
  int g = blockIdx.x, t = threadIdx.x;   // 512 threads
  sdeg[t] = 1.0f;
  __syncthreads();
  unsigned s0 = boff[g], s1 = boff[g + 1];
  for (unsigned i = s0 + t; i < s1; i += W) {
    uint2 p = packed[i];
    atomicAdd(&sdeg[p.x & (W - 1u)], __uint_as_float(p.y));
  }
  __syncthreads();
  int c = g * W + t;
  if (c < n) deg[c] = sdeg[t];
}

// dinv = rsqrt(deg) (deg >= 1 always); g[r] = dinv[r] * h[r]
__global__ void k_dinv(const float* __restrict__ deg, const float* __restrict__ h,
                       float* __restrict__ dinv, float* __restrict__ g, int n) {
  int i = blockIdx.x * blockDim.x + threadIdx.x;
  if (i >= n) return;
  float di = rsqrtf(deg[i]);
  dinv[i] = di;
  g[2 * i]     = di * h[2 * i];
  g[2 * i + 1] = di * h[2 * i + 1];
}

// per-group messages + fused ReLU + score + sort-key build
__global__ void k_gmsg(const uint2* __restrict__ packed, const unsigned* __restrict__ boff,
                       const float* __restrict__ gv, const float* __restrict__ dinv,
                       const float* __restrict__ h, const float* __restrict__ cb,
                       const float* __restrict__ pw, float* __restrict__ out,
                       float* __restrict__ score, unsigned* __restrict__ keys,
                       unsigned* __restrict__ pay, int n) {
  __shared__ float sacc[2 * W];
  int g = blockIdx.x, t = threadIdx.x;   // 512 threads
  sacc[t] = 0.f; sacc[t + W] = 0.f;
  __syncthreads();
  unsigned s0 = boff[g], s1 = boff[g + 1];
  const float2* g2 = (const float2*)gv;
  for (unsigned i = s0 + t; i < s1; i += W) {
    uint2 p = packed[i];
    unsigned r = p.x >> 9;
    unsigned cl = p.x & (W - 1u);
    float a = __uint_as_float(p.y);
    float2 gr = g2[r];
    atomicAdd(&sacc[2 * cl],     a * gr.x);
    atomicAdd(&sacc[2 * cl + 1], a * gr.y);
  }
  __syncthreads();
  int c = g * W + t;
  if (c < n) {
    float dc = dinv[c];
    float o0 = fmaxf(dc * sacc[2 * t]     + dc * dc * h[2 * c]     + cb[0], 0.f);
    float o1 = fmaxf(dc * sacc[2 * t + 1] + dc * dc * h[2 * c + 1] + cb[1], 0.f);
    out[2 * c] = o0; out[2 * c + 1] = o1;
    float pw0 = pw[0], pw1 = pw[1];
    float s = tanhf((o0 * pw0 + o1 * pw1) / sqrtf(pw0 * pw0 + pw1 * pw1));
    score[c] = s;
    unsigned u = __float_as_uint(s);
    unsigned asc = u ^ ((u >> 31) ? 0xFFFFFFFFu : 0x80000000u);
    keys[c] = ~asc;          // descending-order key, sort ascending
    pay[c] = (unsigned)c;
  }
}

// ---------------------------------------------------------------------------
// stable LSD radix sort, 4 x 8-bit passes, chunk=1024/block, table stride BP
// ---------------------------------------------------------------------------
__global__ void k_radix_hist(const unsigned* __restrict__ keys, int n, int shift,
                             unsigned* table) {
  __shared__ unsigned hist[256];
  int t = threadIdx.x;
  hist[t] = 0;
  __syncthreads();
  int base = blockIdx.x * 1024;
  for (int j = 0; j < 4; ++j) {
    int g = base + j * 256 + t;
    if (g < n) {
      unsigned d = (keys[g] >> shift) & 255u;
      atomicAdd(&hist[d], 1u);
    }
  }
  __syncthreads();
  table[t * BP + blockIdx.x] = hist[t];   // digit-major, padded stride
}

// parallel scan over the whole digit-major table (256 rows x B entries)
__global__ void k_radix_scan(unsigned* table, int B) {
  int t = threadIdx.x;                    // 256 threads, one digit row each
  unsigned* row = table + t * BP;
  uint4* r4 = (uint4*)row;
  int nv = B >> 2;                        // 24 vec4 groups for B=98
  unsigned s = 0;
#pragma unroll 8
  for (int i = 0; i < nv; ++i) { uint4 v = r4[i]; s += v.x + v.y + v.z + v.w; }
  for (int i = nv * 4; i < B; ++i) s += row[i];
  // inclusive scan across 256 threads
  int lane = t & 63, w = t >> 6;
  unsigned inc = s;
  for (int off = 1; off < 64; off <<= 1) {
    unsigned nval = __shfl_up(inc, off);
    if (lane >= off) inc += nval;
  }
  __shared__ unsigned wtot[4];
  if (lane == 63) wtot[w] = inc;
  __syncthreads();
  unsigned wpre = 0;
  for (int i = 0; i < w; ++i) wpre += wtot[i];
  unsigned run = wpre + inc - s;          // exclusive prefix of this row
#pragma unroll 8
  for (int i = 0; i < nv; ++i) {
    uint4 v = r4[i]; uint4 o;
    o.x = run; run += v.x; o.y = run; run += v.y;
    o.z = run; run += v.z; o.w = run; run += v.w;
    r4[i] = o;
  }
  for (int i = nv * 4; i < B; ++i) { unsigned v = row[i]; row[i] = run; run += v; }
}

__global__ void k_radix_scatter(const unsigned* __restrict__ keysIn,
                                const unsigned* __restrict__ payIn, int n, int shift,
                                const unsigned* __restrict__ table,
                                unsigned* keysOut, unsigned* payOut) {
  __shared__ unsigned runCnt[256];
  __shared__ unsigned waveCnt[4 * 256];
  int t = threadIdx.x;
  int lane = t & 63, w = t >> 6;
  runCnt[t] = 0;
  int base = blockIdx.x * 1024;
  for (int j = 0; j < 4; ++j) {
    for (int q = t; q < 1024; q += 256) waveCnt[q] = 0;
    __syncthreads();
    int g = base + j * 256 + t;
    bool active = g < n;
    unsigned key = 0, pay = 0, d = 0;
    if (active) { key = keysIn[g]; pay = payIn[g]; d = (key >> shift) & 255u; }
    unsigned long long am = __ballot(active);
    unsigned long long mm = ~0ull;
#pragma unroll
    for (int b = 0; b < 8; ++b) {
      unsigned long long bb = __ballot((d >> b) & 1u);
      mm &= ((d >> b) & 1u) ? bb : ~bb;
    }
    mm &= am;
    int rankw = __popcll(mm & ((1ull << lane) - 1ull));
    if (active && rankw == 0) waveCnt[w * 256 + d] = (unsigned)__popcll(mm);
    __syncthreads();
    if (active) {
      unsigned off = runCnt[d] + (unsigned)rankw;
      for (int ww = 0; ww < w; ++ww) off += waveCnt[ww * 256 + d];
      unsigned gpos = table[d * BP + blockIdx.x] + off;
      keysOut[gpos] = key;
      payOut[gpos] = pay;
    }
    __syncthreads();
    runCnt[t] += waveCnt[t] + waveCnt[256 + t] + waveCnt[512 + t] + waveCnt[768 + t];
    __syncthreads();
  }
}

// ---------------------------------------------------------------------------
// y-pre = sum_j score[perm[j]] * (out[perm[j]] . fc_w[2j:2j+2])
// ---------------------------------------------------------------------------
__global__ void k_final(const unsigned* __restrict__ perm, const float* __restrict__ out,
                        const float* __restrict__ score, const float* __restrict__ fcw,
                        float* acc, int n) {
  int stride = gridDim.x * blockDim.x;
  float s = 0.f;
  for (int j = blockIdx.x * blockDim.x + threadIdx.x; j < n; j += stride) {
    unsigned p = perm[j];
    float sc = score[p];
    s += sc * (out[2 * p] * fcw[2 * j] + out[2 * p + 1] * fcw[2 * j + 1]);
  }
  for (int off = 32; off > 0; off >>= 1) s += __shfl_down(s, off);
  if ((threadIdx.x & 63) == 0) atomic_fadd(acc, s);
}

__global__ void k_sigmoid(const float* acc, const float* __restrict__ fcb, float* y) {
  if (threadIdx.x == 0 && blockIdx.x == 0) {
    float z = *acc + fcb[0];
    y[0] = 1.f / (1.f + expf(-z));
  }
}

// ---------------------------------------------------------------------------
extern "C" void kernel_launch(void* const* d_in, const int* in_sizes, int n_in,
                              void* d_out, int out_size, void* d_ws, size_t ws_size,
                              hipStream_t stream) {
  const float* x     = (const float*)d_in[0];
  const void*  ei    = d_in[1];
  const float* attr  = (const float*)d_in[2];
  const float* convw = (const float*)d_in[3];
  const float* convb = (const float*)d_in[4];
  const float* poolw = (const float*)d_in[5];
  const float* fcw   = (const float*)d_in[6];
  const float* fcb   = (const float*)d_in[7];
  float* y = (float*)d_out;

  int N = in_sizes[0] / FIN;      // 100000
  long long E = in_sizes[2];      // 3200000
  int B = (N + 1023) / 1024;      // score radix chunks (98)
  int G = (N + W - 1) / W;        // 196 coarse groups

  // workspace carve (4-byte units; 8B alignment for uint2/float2 arrays)
  float* ws = (float*)d_ws;
  size_t off = 0;
  uint2* packed  = (uint2*)(ws + off); off += (size_t)2 * E;
  float* h       = ws + off; off += (size_t)2 * N;
  float* deg     = ws + off; off += (size_t)N;
  float* dinv    = ws + off; off += (size_t)N;
  float* gv      = ws + off; off += (size_t)2 * N;
  float* outN    = ws + off; off += (size_t)2 * N;
  float* score   = ws + off; off += (size_t)N;
  unsigned* keysA = (unsigned*)(ws + off); off += (size_t)N;
  unsigned* payA  = (unsigned*)(ws + off); off += (size_t)N;
  unsigned* keysB = (unsigned*)(ws + off); off += (size_t)N;
  unsigned* payB  = (unsigned*)(ws + off); off += (size_t)N;
  unsigned* etab  = (unsigned*)(ws + off); off += (size_t)G * HB;
  unsigned* btot  = (unsigned*)(ws + off); off += (size_t)G;
  unsigned* boff  = (unsigned*)(ws + off); off += (size_t)G + 2;
  unsigned* stab  = (unsigned*)(ws + off); off += (size_t)256 * BP;
  float* acc      = ws + off; off += 1;
  unsigned* mode  = (unsigned*)(ws + off); off += 1;

  int nb = (N + 255) / 256;
  int chunk = (G + 255) / 256;

  k_detect<<<1, 64, 0, stream>>>((const unsigned*)ei, mode, acc);
  k_h<<<(N * 32 + 255) / 256, 256, 0, stream>>>(x, convw, h, N);

  // ---- edge bucketing by destination coarse group ----
  k_hist<<<HB, HT, 0, stream>>>(ei, E, G, etab, mode);
  k_bsum<<<G, 256, 0, stream>>>(etab, btot);
  k_bscan<<<1, 256, 0, stream>>>(btot, boff, G, chunk, (unsigned)E);
  k_bapply<<<G, 256, 0, stream>>>(etab, boff);
  k_scatter<<<HB, HT, 0, stream>>>(ei, attr, E, G, etab, packed, mode);

  // ---- GCN conv via grouped, atomic-free accumulation ----
  k_gdeg<<<G, W, 0, stream>>>(packed, boff, deg, N);
  k_dinv<<<nb, 256, 0, stream>>>(deg, h, dinv, gv, N);
  k_gmsg<<<G, W, 0, stream>>>(packed, boff, gv, dinv, h, convb, poolw,
                              outN, score, keysA, payA, N);

  // ---- 4 stable radix passes: A->B->A->B->A ----
  unsigned* ki = keysA; unsigned* pi = payA;
  unsigned* ko = keysB; unsigned* po = payB;
  for (int p = 0; p < 4; ++p) {
    int shift = 8 * p;
    k_radix_hist<<<B, 256, 0, stream>>>(ki, N, shift, stab);
    k_radix_scan<<<1, 256, 0, stream>>>(stab, B);
    k_radix_scatter<<<B, 256, 0, stream>>>(ki, pi, N, shift, stab, ko, po);
    unsigned* tk = ki; ki = ko; ko = tk;
    unsigned* tp = pi; pi = po; po = tp;
  }
  // perm now in pi (== payA)

  k_final<<<98, 256, 0, stream>>>(pi, outN, score, fcw, acc, N);
  k_sigmoid<<<1, 64, 0, stream>>>(acc, fcb, y);
}